// Round 12
// baseline (3324.920 us; speedup 1.0000x reference)
//
#include <hip/hip_runtime.h>
#include <math.h>

// Problem geometry
#define B_SZ 4
#define S_SZ 4096
#define H_DIM 2048
#define M_TOT (B_SZ * S_SZ)   // 16384 token rows
#define K_DIM H_DIM           // 2048

// Output layout (flat floats, reference return order)
#define OUT_TOKC  0           // [4,4096,1]  16384
#define OUT_CTXC  16384       // [4,1]       4
#define OUT_TASKC 16388       // [4,1]       4
#define OUT_SUPW  16392       // [4,4096,4]  65536
#define OUT_DEPTH 81928       // [4,4096,8]  131072
#define OUT_EFF   213000      // [4,4096,1]  16384
#define OUT_MASK  229384      // [4,4096,4]  65536

// Workspace float-offset header (logits etc.)
#define WS_CTXSUM 0           // 8192
#define WS_HBUF   8192        // 8192
#define WS_TOKL   16384       // 16384  tok logits
#define WS_EFFL   32768       // 16384  eff logits
#define WS_SUPL   49152       // 65536  sup logits [M,4]
#define WS_DEPL   114688      // 131072 dep logits [M,8]
#define NF_MAX    1024
#define WS_FLAGCNT 245760     // 1 int
#define WS_FLAGIDX 245761     // NF_MAX ints
#define WS_RLOG    246788     // NF_MAX*4 floats, init = supb2
#define WS_TOTAL   250884

// Two-phase byte layout (ws_size proven >= 51,380,224; both phases end there).
#define PA_TOKH (1u<<20)
#define PA_TOKL (PA_TOKH + 4194304u)
#define PA_EFFH (PA_TOKL + 4194304u)
#define PA_EFFL (PA_EFFH + 4194304u)
#define PA_X    (PA_EFFL + 4194304u)      // 17,825,792
#define CHUNK_A 4096                      // ends at 51,380,224
#define PB_SUPH (1u<<20)
#define PB_SUPL (PB_SUPH + 8388608u)
#define PB_DEPH (PB_SUPL + 8388608u)
#define PB_DEPL (PB_DEPH + 8388608u)
#define PB_X    (PB_DEPL + 8388608u)      // 34,603,008
#define CHUNK_B 2048                      // ends at 51,380,224

#define BAND 1e-3f

typedef __attribute__((ext_vector_type(8))) short bf16x8s;
typedef __attribute__((ext_vector_type(4))) float f32x4;

__device__ __forceinline__ float gelu_f(float x) {
    return 0.5f * x * (1.0f + erff(x * 0.70710678118654752440f));
}
__device__ __forceinline__ float sigmoid_f(float x) {
    return 1.0f / (1.0f + expf(-x));
}

// split fp32 -> (hi, lo) bf16 by bit truncation; lo captures next 8 mantissa bits.
__device__ __forceinline__ void split4(float4 v, unsigned* hi2, unsigned* lo2) {
    unsigned ux = __float_as_uint(v.x), uy = __float_as_uint(v.y);
    unsigned uz = __float_as_uint(v.z), uw = __float_as_uint(v.w);
    hi2[0] = (ux >> 16) | (uy & 0xffff0000u);
    hi2[1] = (uz >> 16) | (uw & 0xffff0000u);
    float lx = v.x - __uint_as_float(ux & 0xffff0000u);
    float ly = v.y - __uint_as_float(uy & 0xffff0000u);
    float lz = v.z - __uint_as_float(uz & 0xffff0000u);
    float lw = v.w - __uint_as_float(uw & 0xffff0000u);
    lo2[0] = (__float_as_uint(lx) >> 16) | (__float_as_uint(ly) & 0xffff0000u);
    lo2[1] = (__float_as_uint(lz) >> 16) | (__float_as_uint(lw) & 0xffff0000u);
}

// async global->LDS, 16 B per lane. LDS dest = wave-uniform base + lane*16 B.
__device__ __forceinline__ void async16(void* lds, const void* g) {
    __builtin_amdgcn_global_load_lds(
        (const __attribute__((address_space(1))) unsigned int*)g,
        (__attribute__((address_space(3))) unsigned int*)lds,
        16, 0, 0);
}

// ---------------------------------------------------------------------------
__global__ __launch_bounds__(256) void init_ws(float* __restrict__ ws,
        const float* __restrict__ tokb2, const float* __restrict__ effb2,
        const float* __restrict__ supb2, const float* __restrict__ depb2) {
    int i = blockIdx.x * 256 + threadIdx.x;
    if (i >= WS_TOTAL) return;
    float v;
    if (i < WS_TOKL)        v = 0.0f;
    else if (i < WS_EFFL)   v = tokb2[0];
    else if (i < WS_SUPL)   v = effb2[0];
    else if (i < WS_DEPL)   v = supb2[(i - WS_SUPL) & 3];
    else if (i < WS_FLAGCNT) v = depb2[(i - WS_DEPL) & 7];
    else if (i < WS_RLOG)   v = 0.0f;                      // counter + indices (int 0)
    else                    v = supb2[(i - WS_RLOG) & 3];  // repair logit seeds
    ws[i] = v;
}

// ---------------------------------------------------------------------------
// X fp32 rows [row_base, row_base+chunk) -> Xh/Xl bf16 chunk buffers.
__global__ __launch_bounds__(256) void split_x(const float* __restrict__ X,
        unsigned short* __restrict__ Xh, unsigned short* __restrict__ Xl,
        int row_base) {
    size_t i = ((size_t)blockIdx.x * 256 + threadIdx.x) * 8;
    const float* Xo = X + (size_t)row_base * H_DIM;
    float4 a = *(const float4*)&Xo[i];
    float4 b = *(const float4*)&Xo[i + 4];
    unsigned h[4], lo[4];
    split4(a, &h[0], &lo[0]);
    split4(b, &h[2], &lo[2]);
    *(uint4*)&Xh[i] = make_uint4(h[0], h[1], h[2], h[3]);
    *(uint4*)&Xl[i] = make_uint4(lo[0], lo[1], lo[2], lo[3]);
}

// ---------------------------------------------------------------------------
__global__ __launch_bounds__(256) void mean_kernel(const float* __restrict__ X,
                                                   float* __restrict__ ctxsum) {
    int h = blockIdx.x * 256 + threadIdx.x;
    int schunk = blockIdx.y;
    int b = blockIdx.z;
    const float* p = X + ((size_t)b * S_SZ + (size_t)schunk * 128) * H_DIM + h;
    float s = 0.f;
    #pragma unroll 4
    for (int i = 0; i < 128; i++) s += p[(size_t)i * H_DIM];
    atomicAdd(&ctxsum[b * H_DIM + h], s);
}

// ---------------------------------------------------------------------------
__global__ __launch_bounds__(256) void ctx_task_h(const float* __restrict__ ctxsum,
        const float* __restrict__ ctxW1, const float* __restrict__ ctxb1,
        const float* __restrict__ taskW1, const float* __restrict__ taskb1,
        float* __restrict__ hbuf) {
    int j = blockIdx.x * 256 + threadIdx.x;
    int b = blockIdx.y;
    int net = blockIdx.z;
    const float* W1   = net ? taskW1 : ctxW1;
    const float* bias = net ? taskb1 : ctxb1;
    const float* xs = ctxsum + b * H_DIM;
    float s = 0.f;
    #pragma unroll 8
    for (int k = 0; k < H_DIM; k++) s += xs[k] * W1[(size_t)k * 1024 + j];
    float h = gelu_f(s * (1.0f / (float)S_SZ) + bias[j]);
    hbuf[((net * 4 + b) << 10) + j] = h;
}

__global__ __launch_bounds__(256) void ctx_task_out(const float* __restrict__ hbuf,
        const float* __restrict__ ctxW2, const float* __restrict__ ctxb2,
        const float* __restrict__ taskW2, const float* __restrict__ taskb2,
        float* __restrict__ dout) {
    int b = blockIdx.x, net = blockIdx.y;
    const float* W2 = net ? taskW2 : ctxW2;
    const float* h = hbuf + ((net * 4 + b) << 10);
    float s = 0.f;
    #pragma unroll
    for (int jj = 0; jj < 4; jj++) s += h[jj * 256 + threadIdx.x] * W2[jj * 256 + threadIdx.x];
    #pragma unroll
    for (int off = 32; off; off >>= 1) s += __shfl_down(s, off, 64);
    __shared__ float red[4];
    if ((threadIdx.x & 63) == 0) red[threadIdx.x >> 6] = s;
    __syncthreads();
    if (threadIdx.x == 0) {
        float tot = red[0] + red[1] + red[2] + red[3];
        float b2 = net ? taskb2[0] : ctxb2[0];
        dout[OUT_CTXC + net * 4 + b] = sigmoid_f(tot + b2);
    }
}

// ---------------------------------------------------------------------------
// W1 [K=2048][N] fp32  ->  Wh/Wl [N][2048] bf16 (hi/lo split), 64x64 LDS tiles
// ---------------------------------------------------------------------------
__global__ __launch_bounds__(256) void transpose_split(const float* __restrict__ W1,
        unsigned short* __restrict__ Wh, unsigned short* __restrict__ Wl, int N) {
    __shared__ float T[64][68];
    int k0 = blockIdx.x * 64, n0 = blockIdx.y * 64;
    int t = threadIdx.x;
    int tk = t >> 4, tn = (t & 15) * 4;
    #pragma unroll
    for (int i = 0; i < 4; i++) {
        float4 v = *(const float4*)&W1[(size_t)(k0 + tk + i * 16) * N + n0 + tn];
        T[tk + i * 16][tn] = v.x;  T[tk + i * 16][tn + 1] = v.y;
        T[tk + i * 16][tn + 2] = v.z;  T[tk + i * 16][tn + 3] = v.w;
    }
    __syncthreads();
    int n = t >> 2, ks = (t & 3) * 16;
    unsigned hi[8], lo[8];
    #pragma unroll
    for (int j = 0; j < 16; j += 4) {
        float4 v = make_float4(T[ks + j][n], T[ks + j + 1][n],
                               T[ks + j + 2][n], T[ks + j + 3][n]);
        split4(v, &hi[j >> 1], &lo[j >> 1]);
    }
    size_t o = (size_t)(n0 + n) * 2048 + k0 + ks;
    *(uint4*)&Wh[o]     = make_uint4(hi[0], hi[1], hi[2], hi[3]);
    *(uint4*)&Wh[o + 8] = make_uint4(hi[4], hi[5], hi[6], hi[7]);
    *(uint4*)&Wl[o]     = make_uint4(lo[0], lo[1], lo[2], lo[3]);
    *(uint4*)&Wl[o + 8] = make_uint4(lo[4], lo[5], lo[6], lo[7]);
}

// ---------------------------------------------------------------------------
// Epilogue: second linear layer (N->P) + per-row reduce + atomic accumulate.
// acc is [2][2] (mt, nt) for the 32x32 per-wave subtile.
// ---------------------------------------------------------------------------
template<int P>
__device__ __forceinline__ void epi(f32x4 (&acc)[2][2], const float* __restrict__ W2,
        float* __restrict__ out_logit, int n0, int wave_n, int wave_m,
        int m0g, int lr, int kq) {
    #pragma unroll
    for (int p = 0; p < P; p++) {
        float w2v[2];
        #pragma unroll
        for (int nt = 0; nt < 2; nt++)
            w2v[nt] = W2[(size_t)(n0 + wave_n + nt * 16 + lr) * P + p];
        #pragma unroll
        for (int mt = 0; mt < 2; mt++) {
            int mbase = m0g + wave_m + mt * 16 + kq * 4;
            #pragma unroll
            for (int j = 0; j < 4; j++) {
                float s = acc[mt][0][j] * w2v[0] + acc[mt][1][j] * w2v[1];
                s += __shfl_xor(s, 1, 64);
                s += __shfl_xor(s, 2, 64);
                s += __shfl_xor(s, 4, 64);
                s += __shfl_xor(s, 8, 64);
                if (lr == p) atomicAdd(&out_logit[(size_t)(mbase + j) * P + p], s);
            }
        }
    }
}

// ---------------------------------------------------------------------------
// Combined split-bf16 MFMA MLP GEMM, 64x64 tile, single-buffered 16 KiB LDS,
// m97-style 2-barrier K-loop. Occupancy trajectory (measured): 2 blocks/CU ->
// 27 G-MFMA/s, 4 blocks/CU -> 35 G-MFMA/s; this version gives grid=2048 with
// __launch_bounds__(256,8) -> 8 blocks/CU (32 waves, full) so inter-block TLP
// hides the vmcnt(0) barrier drain further.
// Waves: 2M x 2N; wave w owns rows (w&1)*32..+32, cols (w>>1)*32..+32.
// MODE 0: tok||eff (N=1024/net, 16 n-blocks/net, P=1).    grid(32, chunk/64)
// MODE 1: sup||dep (N=2048/net, 32 n-blocks/net, P=4/8).  grid(64, chunk/64)
// LDS swizzle: chunk c of row r at LDS chunk c ^ ((r>>1)&3); gload source
// pre-swizzled per-lane kc = (l&3) ^ ((l>>3)&3) (valid for 16-aligned bases).
// ---------------------------------------------------------------------------
template<int MODE>
__global__ __launch_bounds__(256, 8) void mfma2(
        const unsigned short* __restrict__ Xh, const unsigned short* __restrict__ Xl,
        const unsigned short* __restrict__ WhA, const unsigned short* __restrict__ WlA,
        const unsigned short* __restrict__ WhB, const unsigned short* __restrict__ WlB,
        const float* __restrict__ fixA, const float* __restrict__ fixB,
        const float* __restrict__ b1A, const float* __restrict__ b1B,
        const float* __restrict__ W2A, const float* __restrict__ W2B,
        const float* __restrict__ tokc, const float* __restrict__ ccp,
        const float* __restrict__ tkp,
        float* __restrict__ outA, float* __restrict__ outB, int m_base) {
    __shared__ unsigned short Ah[64 * 32], Al[64 * 32];    // 4 KiB each
    __shared__ unsigned short Bh[64 * 32], Bl[64 * 32];    // 4 KiB each

    constexpr int NBLK = (MODE == 0) ? 16 : 32;
    const int t = threadIdx.x;
    const int lane = t & 63;
    const int w = t >> 6;
    const int wave_m = (w & 1) * 32;
    const int wave_n = (w >> 1) * 32;
    const int net = (int)blockIdx.x >= NBLK;
    const int n0 = ((int)blockIdx.x - (net ? NBLK : 0)) * 64;
    const int m0l = blockIdx.y * 64;         // chunk-local row base (Xh/Xl)
    const int m0g = m_base + m0l;            // global row base (outputs)

    const unsigned short* Wth = net ? WhB : WhA;
    const unsigned short* Wtl = net ? WlB : WlA;

    // staging: wave w fills rows [w*16, w*16+16) of each of Ah/Al/Bh/Bl
    const int sr = lane >> 2;                         // row within 16-row group
    const int kc = (lane & 3) ^ ((lane >> 3) & 3);    // pre-swizzled k-chunk
    size_t oA = (size_t)(m0l + w * 16 + sr) * K_DIM + kc * 8;
    size_t oB = (size_t)(n0 + w * 16 + sr) * K_DIM + kc * 8;
    const unsigned short* gAh = Xh + oA;
    const unsigned short* gAl = Xl + oA;
    const unsigned short* gBh = Wth + oB;
    const unsigned short* gBl = Wtl + oB;
    const int ld = (w * 16) * 32;            // wave-uniform LDS elem offset

    const int lr = lane & 15;
    const int kq = lane >> 4;
    const int coff = ((kq ^ ((lr >> 1) & 3)) * 8);

    f32x4 acc[2][2];
    #pragma unroll
    for (int i = 0; i < 2; i++)
        #pragma unroll
        for (int j = 0; j < 2; j++) acc[i][j] = (f32x4){0.f, 0.f, 0.f, 0.f};

    for (int k0 = 0; k0 < K_DIM; k0 += 32) {
        __syncthreads();                 // all waves done reading previous tile
        async16(&Ah[ld], gAh + k0);
        async16(&Al[ld], gAl + k0);
        async16(&Bh[ld], gBh + k0);
        async16(&Bl[ld], gBl + k0);
        __syncthreads();                 // vmcnt(0) drain -> tile visible

        bf16x8s ahf[2], alf[2];
        #pragma unroll
        for (int mt = 0; mt < 2; mt++) {
            int r = (wave_m + mt * 16 + lr) * 32 + coff;
            ahf[mt] = *(const bf16x8s*)&Ah[r];
            alf[mt] = *(const bf16x8s*)&Al[r];
        }
        #pragma unroll
        for (int nt = 0; nt < 2; nt++) {
            int rb = (wave_n + nt * 16 + lr) * 32 + coff;
            bf16x8s bh = *(const bf16x8s*)&Bh[rb];
            bf16x8s bl = *(const bf16x8s*)&Bl[rb];
            #pragma unroll
            for (int mt = 0; mt < 2; mt++) {
                acc[mt][nt] = __builtin_amdgcn_mfma_f32_16x16x32_bf16(ahf[mt], bh, acc[mt][nt], 0, 0, 0);
                acc[mt][nt] = __builtin_amdgcn_mfma_f32_16x16x32_bf16(ahf[mt], bl, acc[mt][nt], 0, 0, 0);
                acc[mt][nt] = __builtin_amdgcn_mfma_f32_16x16x32_bf16(alf[mt], bh, acc[mt][nt], 0, 0, 0);
            }
        }
    }

    // ---- bias / fixup / GELU
    const float* b1 = net ? b1B : b1A;
    float ccv = 0.f, tkv = 0.f;
    const float* fx = nullptr;
    if constexpr (MODE == 1) {
        int batch = m0g >> 12;               // 4096 rows per batch
        ccv = ccp[batch];
        tkv = tkp[batch];
        fx = net ? fixB : fixA;
    }
    #pragma unroll
    for (int mt = 0; mt < 2; mt++) {
        int mbase = m0g + wave_m + mt * 16 + kq * 4;
        f32x4 tc4 = (f32x4){0.f, 0.f, 0.f, 0.f};
        if constexpr (MODE == 1) tc4 = *(const f32x4*)&tokc[mbase];
        #pragma unroll
        for (int nt = 0; nt < 2; nt++) {
            int n = n0 + wave_n + nt * 16 + lr;
            float bias = b1[n];
            float f1 = 0.f, f2 = 0.f, f3 = 0.f;
            if constexpr (MODE == 1) {
                f1 = fx[(size_t)2048 * 2048 + n];
                f2 = fx[(size_t)2049 * 2048 + n];
                f3 = fx[(size_t)2050 * 2048 + n];
            }
            #pragma unroll
            for (int j = 0; j < 4; j++) {
                float h = acc[mt][nt][j] + bias;
                if constexpr (MODE == 1) h += tc4[j] * f1 + ccv * f2 + tkv * f3;
                acc[mt][nt][j] = gelu_f(h);
            }
        }
    }

    // ---- second layer + atomic accumulate
    if constexpr (MODE == 0) {
        epi<1>(acc, net ? W2B : W2A, net ? outB : outA, n0, wave_n, wave_m, m0g, lr, kq);
    } else {
        if (net == 0) epi<4>(acc, W2A, outA, n0, wave_n, wave_m, m0g, lr, kq);
        else          epi<8>(acc, W2B, outB, n0, wave_n, wave_m, m0g, lr, kq);
    }
}

// ---------------------------------------------------------------------------
// sigmoid of tok/eff logits for rows [row_base, row_base + grid*256)
__global__ __launch_bounds__(256) void finalize1(const float* __restrict__ ws,
                                                 float* __restrict__ dout,
                                                 int row_base) {
    int r = row_base + blockIdx.x * 256 + threadIdx.x;
    dout[OUT_TOKC + r] = sigmoid_f(ws[WS_TOKL + r]);
    dout[OUT_EFF + r]  = sigmoid_f(ws[WS_EFFL + r]);
}

// softmax + mask; flags rows whose sup_w is borderline-near 0.2 for fp32 repair
__global__ __launch_bounds__(256) void finalize2(float* __restrict__ ws,
                                                 float* __restrict__ dout) {
    int r = blockIdx.x * 256 + threadIdx.x;
    const float* sl = ws + WS_SUPL + (size_t)r * 4;
    float l[4];
    #pragma unroll
    for (int i = 0; i < 4; i++) l[i] = sl[i];
    float mx = fmaxf(fmaxf(l[0], l[1]), fmaxf(l[2], l[3]));
    float e[4], sum = 0.f;
    #pragma unroll
    for (int i = 0; i < 4; i++) { e[i] = expf(l[i] - mx); sum += e[i]; }
    float inv = 1.0f / sum;
    float eff = dout[OUT_EFF + r];
    bool flag = false;
    #pragma unroll
    for (int i = 0; i < 4; i++) {
        float wv = e[i] * inv;
        dout[OUT_SUPW + (size_t)r * 4 + i] = wv;
        dout[OUT_MASK + (size_t)r * 4 + i] = (wv > 0.2f) ? eff : 0.f;
        flag = flag || (fabsf(wv - 0.2f) < BAND);
    }
    if (flag) {
        int* cnt = (int*)(ws + WS_FLAGCNT);
        int* idx = (int*)(ws + WS_FLAGIDX);
        int slot = atomicAdd(cnt, 1);
        if (slot < NF_MAX) idx[slot] = r;
    }
    const float* dl = ws + WS_DEPL + (size_t)r * 8;
    float d[8];
    #pragma unroll
    for (int i = 0; i < 8; i++) d[i] = dl[i];
    float mx2 = d[0];
    #pragma unroll
    for (int i = 1; i < 8; i++) mx2 = fmaxf(mx2, d[i]);
    float sum2 = 0.f;
    #pragma unroll
    for (int i = 0; i < 8; i++) { d[i] = expf(d[i] - mx2); sum2 += d[i]; }
    float inv2 = 1.0f / sum2;
    #pragma unroll
    for (int i = 0; i < 8; i++)
        dout[OUT_DEPTH + (size_t)r * 8 + i] = d[i] * inv2;
}

// ---------------------------------------------------------------------------
// fp32 repair of sup logits for flagged rows.
// ---------------------------------------------------------------------------
__global__ __launch_bounds__(256) void repair_h(const float* __restrict__ X,
        const float* __restrict__ W1, const float* __restrict__ b1,
        const float* __restrict__ W2, const float* __restrict__ dout,
        const int* __restrict__ cntp, const int* __restrict__ idxp,
        float* __restrict__ rlog) {
    int cnt = *cntp; if (cnt > NF_MAX) cnt = NF_MAX;
    int rbase = blockIdx.y * 8;
    if (rbase >= cnt) return;
    int nr = cnt - rbase; if (nr > 8) nr = 8;

    __shared__ float Xs[8][2048];   // 64 KB
    __shared__ float HS[8][128];    // upper-k partial h

    const int t = threadIdx.x;
    const int w = t >> 6;
    const int lane = t & 63;
    const int joff = (w & 1) * 64 + lane;      // 0..127
    const int kh = w >> 1;                     // 0 or 1
    const int j = blockIdx.x * 128 + joff;

    int rows[8];
    #pragma unroll
    for (int rr = 0; rr < 8; rr++)
        rows[rr] = idxp[rbase + (rr < nr ? rr : 0)];

    for (int rr = 0; rr < nr; rr++) {
        const float4* src = (const float4*)(X + (size_t)rows[rr] * 2048);
        for (int c = t; c < 512; c += 256) ((float4*)Xs[rr])[c] = src[c];
    }
    for (int rr = nr; rr < 8; rr++)
        for (int c = t; c < 2048; c += 256) Xs[rr][c] = 0.f;
    __syncthreads();

    float h[8] = {0.f, 0.f, 0.f, 0.f, 0.f, 0.f, 0.f, 0.f};
    const float* Wcol = W1 + j;
    for (int k = kh * 1024; k < kh * 1024 + 1024; k += 4) {
        float w0 = Wcol[(size_t)(k + 0) * 2048];
        float w1 = Wcol[(size_t)(k + 1) * 2048];
        float w2 = Wcol[(size_t)(k + 2) * 2048];
        float w3 = Wcol[(size_t)(k + 3) * 2048];
        #pragma unroll
        for (int rr = 0; rr < 8; rr++) {
            float4 xv = *(const float4*)&Xs[rr][k];
            h[rr] = fmaf(xv.x, w0, h[rr]);
            h[rr] = fmaf(xv.y, w1, h[rr]);
            h[rr] = fmaf(xv.z, w2, h[rr]);
            h[rr] = fmaf(xv.w, w3, h[rr]);
        }
    }
    if (kh == 1) {
        #pragma unroll
        for (int rr = 0; rr < 8; rr++) HS[rr][joff] = h[rr];
    }
    __syncthreads();
    if (kh == 0) {
        float f1 = W1[(size_t)2048 * 2048 + j];
        float f2 = W1[(size_t)2049 * 2048 + j];
        float f3 = W1[(size_t)2050 * 2048 + j];
        float bj = b1[j];
        float4 w2v = *(const float4*)&W2[(size_t)j * 4];
        for (int rr = 0; rr < nr; rr++) {
            int r = rows[rr];
            float tc = dout[OUT_TOKC + r];
            float cc = dout[OUT_CTXC + (r >> 12)];
            float tk = dout[OUT_TASKC + (r >> 12)];
            float ht = h[rr] + HS[rr][joff] + tc * f1 + cc * f2 + tk * f3 + bj;
            float g = gelu_f(ht);
            float s0 = g * w2v.x, s1 = g * w2v.y, s2 = g * w2v.z, s3 = g * w2v.w;
            #pragma unroll
            for (int off = 1; off < 64; off <<= 1) {
                s0 += __shfl_xor(s0, off, 64);
                s1 += __shfl_xor(s1, off, 64);
                s2 += __shfl_xor(s2, off, 64);
                s3 += __shfl_xor(s3, off, 64);
            }
            if (lane == 0) {
                float* rl = rlog + (size_t)(rbase + rr) * 4;
                atomicAdd(&rl[0], s0);
                atomicAdd(&rl[1], s1);
                atomicAdd(&rl[2], s2);
                atomicAdd(&rl[3], s3);
            }
        }
    }
}

// overwrite supw + mask rows for flagged tokens from fp32 logits
__global__ __launch_bounds__(256) void repair_fin(const int* __restrict__ cntp,
        const int* __restrict__ idxp, const float* __restrict__ rlog,
        float* __restrict__ dout) {
    int cnt = *cntp; if (cnt > NF_MAX) cnt = NF_MAX;
    int slot = blockIdx.x * 256 + threadIdx.x;
    if (slot >= cnt) return;
    int r = idxp[slot];
    float l[4];
    #pragma unroll
    for (int i = 0; i < 4; i++) l[i] = rlog[(size_t)slot * 4 + i];
    float mx = fmaxf(fmaxf(l[0], l[1]), fmaxf(l[2], l[3]));
    float e[4], sum = 0.f;
    #pragma unroll
    for (int i = 0; i < 4; i++) { e[i] = expf(l[i] - mx); sum += e[i]; }
    float inv = 1.0f / sum;
    float eff = dout[OUT_EFF + r];
    #pragma unroll
    for (int i = 0; i < 4; i++) {
        float wv = e[i] * inv;
        dout[OUT_SUPW + (size_t)r * 4 + i] = wv;
        dout[OUT_MASK + (size_t)r * 4 + i] = (wv > 0.2f) ? eff : 0.f;
    }
}

// ---------------------------------------------------------------------------
extern "C" void kernel_launch(void* const* d_in, const int* in_sizes, int n_in,
                              void* d_out, int out_size, void* d_ws, size_t ws_size,
                              hipStream_t stream) {
    const float* X      = (const float*)d_in[0];
    const float* tokW1  = (const float*)d_in[1];
    const float* tokb1  = (const float*)d_in[2];
    const float* tokW2  = (const float*)d_in[3];
    const float* tokb2  = (const float*)d_in[4];
    const float* ctxW1  = (const float*)d_in[5];
    const float* ctxb1  = (const float*)d_in[6];
    const float* ctxW2  = (const float*)d_in[7];
    const float* ctxb2  = (const float*)d_in[8];
    const float* taskW1 = (const float*)d_in[9];
    const float* taskb1 = (const float*)d_in[10];
    const float* taskW2 = (const float*)d_in[11];
    const float* taskb2 = (const float*)d_in[12];
    const float* effW1  = (const float*)d_in[13];
    const float* effb1  = (const float*)d_in[14];
    const float* effW2  = (const float*)d_in[15];
    const float* effb2  = (const float*)d_in[16];
    const float* supW1  = (const float*)d_in[17];
    const float* supb1  = (const float*)d_in[18];
    const float* supW2  = (const float*)d_in[19];
    const float* supb2  = (const float*)d_in[20];
    const float* depW1  = (const float*)d_in[21];
    const float* depb1  = (const float*)d_in[22];
    const float* depW2  = (const float*)d_in[23];
    const float* depb2  = (const float*)d_in[24];
    float* out = (float*)d_out;
    float* ws  = (float*)d_ws;
    char*  wsb = (char*)d_ws;

    // Phase A pointers
    unsigned short* tokh = (unsigned short*)(wsb + PA_TOKH);
    unsigned short* tokl = (unsigned short*)(wsb + PA_TOKL);
    unsigned short* effh = (unsigned short*)(wsb + PA_EFFH);
    unsigned short* effl = (unsigned short*)(wsb + PA_EFFL);
    unsigned short* xa   = (unsigned short*)(wsb + PA_X);
    unsigned short* xal  = xa + (size_t)CHUNK_A * H_DIM;
    // Phase B pointers (overlap phase A region; stream-ordered)
    unsigned short* suph = (unsigned short*)(wsb + PB_SUPH);
    unsigned short* supl = (unsigned short*)(wsb + PB_SUPL);
    unsigned short* deph = (unsigned short*)(wsb + PB_DEPH);
    unsigned short* depl = (unsigned short*)(wsb + PB_DEPL);
    unsigned short* xb   = (unsigned short*)(wsb + PB_X);
    unsigned short* xbl  = xb + (size_t)CHUNK_B * H_DIM;

    const int* cntp = (const int*)(ws + WS_FLAGCNT);
    const int* idxp = (const int*)(ws + WS_FLAGIDX);
    float* rlog = ws + WS_RLOG;

    init_ws<<<(WS_TOTAL + 255) / 256, 256, 0, stream>>>(ws, tokb2, effb2, supb2, depb2);
    mean_kernel<<<dim3(8, 32, 4), 256, 0, stream>>>(X, ws + WS_CTXSUM);
    ctx_task_h<<<dim3(4, 4, 2), 256, 0, stream>>>(ws + WS_CTXSUM, ctxW1, ctxb1,
                                                  taskW1, taskb1, ws + WS_HBUF);
    ctx_task_out<<<dim3(4, 2), 256, 0, stream>>>(ws + WS_HBUF, ctxW2, ctxb2,
                                                 taskW2, taskb2, out);

    // ---- Phase A: tok + eff ----
    transpose_split<<<dim3(32, 16), 256, 0, stream>>>(tokW1, tokh, tokl, 1024);
    transpose_split<<<dim3(32, 16), 256, 0, stream>>>(effW1, effh, effl, 1024);
    for (int c0 = 0; c0 < M_TOT; c0 += CHUNK_A) {
        split_x<<<CHUNK_A, 256, 0, stream>>>(X, xa, xal, c0);
        mfma2<0><<<dim3(32, CHUNK_A / 64), 256, 0, stream>>>(
            xa, xal, tokh, tokl, effh, effl,
            nullptr, nullptr, tokb1, effb1, tokW2, effW2,
            nullptr, nullptr, nullptr,
            ws + WS_TOKL, ws + WS_EFFL, c0);
        finalize1<<<CHUNK_A / 256, 256, 0, stream>>>(ws, out, c0);
    }

    // ---- Phase B: sup + dep (weights overwrite phase A area) ----
    transpose_split<<<dim3(32, 32), 256, 0, stream>>>(supW1, suph, supl, 2048);
    transpose_split<<<dim3(32, 32), 256, 0, stream>>>(depW1, deph, depl, 2048);
    for (int c0 = 0; c0 < M_TOT; c0 += CHUNK_B) {
        split_x<<<CHUNK_B, 256, 0, stream>>>(X, xb, xbl, c0);
        mfma2<1><<<dim3(64, CHUNK_B / 64), 256, 0, stream>>>(
            xb, xbl, suph, supl, deph, depl,
            supW1, depW1, supb1, depb1, supW2, depW2,
            out + OUT_TOKC, out + OUT_CTXC, out + OUT_TASKC,
            ws + WS_SUPL, ws + WS_DEPL, c0);
    }

    finalize2<<<64, 256, 0, stream>>>(ws, out);
    repair_h<<<dim3(16, NF_MAX / 8), 256, 0, stream>>>(
        X, supW1, supb1, supW2, out, cntp, idxp, rlog);
    repair_fin<<<NF_MAX / 256, 256, 0, stream>>>(cntp, idxp, rlog, out);
}

// Round 13
// 2419.644 us; speedup vs baseline: 1.3741x; 1.3741x over previous
//
#include <hip/hip_runtime.h>
#include <math.h>

// Problem geometry
#define B_SZ 4
#define S_SZ 4096
#define H_DIM 2048
#define M_TOT (B_SZ * S_SZ)   // 16384 token rows
#define K_DIM H_DIM           // 2048

// Output layout (flat floats, reference return order)
#define OUT_TOKC  0           // [4,4096,1]  16384
#define OUT_CTXC  16384       // [4,1]       4
#define OUT_TASKC 16388       // [4,1]       4
#define OUT_SUPW  16392       // [4,4096,4]  65536
#define OUT_DEPTH 81928       // [4,4096,8]  131072
#define OUT_EFF   213000      // [4,4096,1]  16384
#define OUT_MASK  229384      // [4,4096,4]  65536

// Workspace float-offset header (logits etc.)
#define WS_CTXSUM 0           // 8192
#define WS_HBUF   8192        // 8192
#define WS_TOKL   16384       // 16384  tok logits
#define WS_EFFL   32768       // 16384  eff logits
#define WS_SUPL   49152       // 65536  sup logits [M,4]
#define WS_DEPL   114688      // 131072 dep logits [M,8]
#define NF_MAX    1024
#define WS_FLAGCNT 245760     // 1 int
#define WS_FLAGIDX 245761     // NF_MAX ints
#define WS_RLOG    246788     // NF_MAX*4 floats, init = supb2
#define WS_TOTAL   250884

// Two-phase byte layout (ws_size proven >= 51,380,224; both phases end there).
#define PA_TOKH (1u<<20)
#define PA_TOKL (PA_TOKH + 4194304u)
#define PA_EFFH (PA_TOKL + 4194304u)
#define PA_EFFL (PA_EFFH + 4194304u)
#define PA_X    (PA_EFFL + 4194304u)      // 17,825,792
#define CHUNK_A 4096                      // ends at 51,380,224
#define PB_SUPH (1u<<20)
#define PB_SUPL (PB_SUPH + 8388608u)
#define PB_DEPH (PB_SUPL + 8388608u)
#define PB_DEPL (PB_DEPH + 8388608u)
#define PB_X    (PB_DEPL + 8388608u)      // 34,603,008
#define CHUNK_B 2048                      // ends at 51,380,224

#define BAND 1e-3f

typedef __attribute__((ext_vector_type(8))) short bf16x8s;
typedef __attribute__((ext_vector_type(4))) float f32x4;

__device__ __forceinline__ float gelu_f(float x) {
    return 0.5f * x * (1.0f + erff(x * 0.70710678118654752440f));
}
__device__ __forceinline__ float sigmoid_f(float x) {
    return 1.0f / (1.0f + expf(-x));
}

// split fp32 -> (hi, lo) bf16 by bit truncation; lo captures next 8 mantissa bits.
__device__ __forceinline__ void split4(float4 v, unsigned* hi2, unsigned* lo2) {
    unsigned ux = __float_as_uint(v.x), uy = __float_as_uint(v.y);
    unsigned uz = __float_as_uint(v.z), uw = __float_as_uint(v.w);
    hi2[0] = (ux >> 16) | (uy & 0xffff0000u);
    hi2[1] = (uz >> 16) | (uw & 0xffff0000u);
    float lx = v.x - __uint_as_float(ux & 0xffff0000u);
    float ly = v.y - __uint_as_float(uy & 0xffff0000u);
    float lz = v.z - __uint_as_float(uz & 0xffff0000u);
    float lw = v.w - __uint_as_float(uw & 0xffff0000u);
    lo2[0] = (__float_as_uint(lx) >> 16) | (__float_as_uint(ly) & 0xffff0000u);
    lo2[1] = (__float_as_uint(lz) >> 16) | (__float_as_uint(lw) & 0xffff0000u);
}

// async global->LDS, 16 B per lane. LDS dest = wave-uniform base + lane*16 B.
__device__ __forceinline__ void async16(void* lds, const void* g) {
    __builtin_amdgcn_global_load_lds(
        (const __attribute__((address_space(1))) unsigned int*)g,
        (__attribute__((address_space(3))) unsigned int*)lds,
        16, 0, 0);
}

// ---------------------------------------------------------------------------
__global__ __launch_bounds__(256) void init_ws(float* __restrict__ ws,
        const float* __restrict__ tokb2, const float* __restrict__ effb2,
        const float* __restrict__ supb2, const float* __restrict__ depb2) {
    int i = blockIdx.x * 256 + threadIdx.x;
    if (i >= WS_TOTAL) return;
    float v;
    if (i < WS_TOKL)        v = 0.0f;
    else if (i < WS_EFFL)   v = tokb2[0];
    else if (i < WS_SUPL)   v = effb2[0];
    else if (i < WS_DEPL)   v = supb2[(i - WS_SUPL) & 3];
    else if (i < WS_FLAGCNT) v = depb2[(i - WS_DEPL) & 7];
    else if (i < WS_RLOG)   v = 0.0f;                      // counter + indices (int 0)
    else                    v = supb2[(i - WS_RLOG) & 3];  // repair logit seeds
    ws[i] = v;
}

// ---------------------------------------------------------------------------
// X fp32 rows [row_base, row_base+chunk) -> Xh/Xl bf16 chunk buffers.
__global__ __launch_bounds__(256) void split_x(const float* __restrict__ X,
        unsigned short* __restrict__ Xh, unsigned short* __restrict__ Xl,
        int row_base) {
    size_t i = ((size_t)blockIdx.x * 256 + threadIdx.x) * 8;
    const float* Xo = X + (size_t)row_base * H_DIM;
    float4 a = *(const float4*)&Xo[i];
    float4 b = *(const float4*)&Xo[i + 4];
    unsigned h[4], lo[4];
    split4(a, &h[0], &lo[0]);
    split4(b, &h[2], &lo[2]);
    *(uint4*)&Xh[i] = make_uint4(h[0], h[1], h[2], h[3]);
    *(uint4*)&Xl[i] = make_uint4(lo[0], lo[1], lo[2], lo[3]);
}

// ---------------------------------------------------------------------------
__global__ __launch_bounds__(256) void mean_kernel(const float* __restrict__ X,
                                                   float* __restrict__ ctxsum) {
    int h = blockIdx.x * 256 + threadIdx.x;
    int schunk = blockIdx.y;
    int b = blockIdx.z;
    const float* p = X + ((size_t)b * S_SZ + (size_t)schunk * 128) * H_DIM + h;
    float s = 0.f;
    #pragma unroll 4
    for (int i = 0; i < 128; i++) s += p[(size_t)i * H_DIM];
    atomicAdd(&ctxsum[b * H_DIM + h], s);
}

// ---------------------------------------------------------------------------
__global__ __launch_bounds__(256) void ctx_task_h(const float* __restrict__ ctxsum,
        const float* __restrict__ ctxW1, const float* __restrict__ ctxb1,
        const float* __restrict__ taskW1, const float* __restrict__ taskb1,
        float* __restrict__ hbuf) {
    int j = blockIdx.x * 256 + threadIdx.x;
    int b = blockIdx.y;
    int net = blockIdx.z;
    const float* W1   = net ? taskW1 : ctxW1;
    const float* bias = net ? taskb1 : ctxb1;
    const float* xs = ctxsum + b * H_DIM;
    float s = 0.f;
    #pragma unroll 8
    for (int k = 0; k < H_DIM; k++) s += xs[k] * W1[(size_t)k * 1024 + j];
    float h = gelu_f(s * (1.0f / (float)S_SZ) + bias[j]);
    hbuf[((net * 4 + b) << 10) + j] = h;
}

__global__ __launch_bounds__(256) void ctx_task_out(const float* __restrict__ hbuf,
        const float* __restrict__ ctxW2, const float* __restrict__ ctxb2,
        const float* __restrict__ taskW2, const float* __restrict__ taskb2,
        float* __restrict__ dout) {
    int b = blockIdx.x, net = blockIdx.y;
    const float* W2 = net ? taskW2 : ctxW2;
    const float* h = hbuf + ((net * 4 + b) << 10);
    float s = 0.f;
    #pragma unroll
    for (int jj = 0; jj < 4; jj++) s += h[jj * 256 + threadIdx.x] * W2[jj * 256 + threadIdx.x];
    #pragma unroll
    for (int off = 32; off; off >>= 1) s += __shfl_down(s, off, 64);
    __shared__ float red[4];
    if ((threadIdx.x & 63) == 0) red[threadIdx.x >> 6] = s;
    __syncthreads();
    if (threadIdx.x == 0) {
        float tot = red[0] + red[1] + red[2] + red[3];
        float b2 = net ? taskb2[0] : ctxb2[0];
        dout[OUT_CTXC + net * 4 + b] = sigmoid_f(tot + b2);
    }
}

// ---------------------------------------------------------------------------
// W1 [K=2048][N] fp32  ->  Wh/Wl [N][2048] bf16 (hi/lo split), 64x64 LDS tiles
// ---------------------------------------------------------------------------
__global__ __launch_bounds__(256) void transpose_split(const float* __restrict__ W1,
        unsigned short* __restrict__ Wh, unsigned short* __restrict__ Wl, int N) {
    __shared__ float T[64][68];
    int k0 = blockIdx.x * 64, n0 = blockIdx.y * 64;
    int t = threadIdx.x;
    int tk = t >> 4, tn = (t & 15) * 4;
    #pragma unroll
    for (int i = 0; i < 4; i++) {
        float4 v = *(const float4*)&W1[(size_t)(k0 + tk + i * 16) * N + n0 + tn];
        T[tk + i * 16][tn] = v.x;  T[tk + i * 16][tn + 1] = v.y;
        T[tk + i * 16][tn + 2] = v.z;  T[tk + i * 16][tn + 3] = v.w;
    }
    __syncthreads();
    int n = t >> 2, ks = (t & 3) * 16;
    unsigned hi[8], lo[8];
    #pragma unroll
    for (int j = 0; j < 16; j += 4) {
        float4 v = make_float4(T[ks + j][n], T[ks + j + 1][n],
                               T[ks + j + 2][n], T[ks + j + 3][n]);
        split4(v, &hi[j >> 1], &lo[j >> 1]);
    }
    size_t o = (size_t)(n0 + n) * 2048 + k0 + ks;
    *(uint4*)&Wh[o]     = make_uint4(hi[0], hi[1], hi[2], hi[3]);
    *(uint4*)&Wh[o + 8] = make_uint4(hi[4], hi[5], hi[6], hi[7]);
    *(uint4*)&Wl[o]     = make_uint4(lo[0], lo[1], lo[2], lo[3]);
    *(uint4*)&Wl[o + 8] = make_uint4(lo[4], lo[5], lo[6], lo[7]);
}

// ---------------------------------------------------------------------------
// Epilogue: second linear layer (N->P) + per-row reduce + atomic accumulate.
// acc is [2][4] (mt, nt) for the 32x64 per-wave subtile.
// ---------------------------------------------------------------------------
template<int P>
__device__ __forceinline__ void epi(f32x4 (&acc)[2][4], const float* __restrict__ W2,
        float* __restrict__ out_logit, int n0, int wave_n, int wave_m,
        int m0g, int lr, int kq) {
    #pragma unroll
    for (int p = 0; p < P; p++) {
        float w2v[4];
        #pragma unroll
        for (int nt = 0; nt < 4; nt++)
            w2v[nt] = W2[(size_t)(n0 + wave_n + nt * 16 + lr) * P + p];
        #pragma unroll
        for (int mt = 0; mt < 2; mt++) {
            int mbase = m0g + wave_m + mt * 16 + kq * 4;
            #pragma unroll
            for (int j = 0; j < 4; j++) {
                float s = acc[mt][0][j] * w2v[0] + acc[mt][1][j] * w2v[1]
                        + acc[mt][2][j] * w2v[2] + acc[mt][3][j] * w2v[3];
                s += __shfl_xor(s, 1, 64);
                s += __shfl_xor(s, 2, 64);
                s += __shfl_xor(s, 4, 64);
                s += __shfl_xor(s, 8, 64);
                if (lr == p) atomicAdd(&out_logit[(size_t)(mbase + j) * P + p], s);
            }
        }
    }
}

// ---------------------------------------------------------------------------
// Combined split-bf16 MFMA MLP GEMM, 64x128 tile (measured best: 35 G-MFMA/s
// at 4 blocks/CU; 64x64@8/CU regressed to 22 via staging-BW saturation).
// GRID TRANSPOSED for L2 locality: blockIdx.x (fastest) = m-tile, blockIdx.y
// = n-tile, so consecutively-dispatched blocks share one 1-MiB B-panel
// (L2-resident per XCD) and stream the L3-resident A chunk. Round-11 FETCH
// was 2.4x compulsory (B re-reads missing L2); this targets that.
// Waves: 2M x 2N; wave w owns rows (w&1)*32..+32, cols (w>>1)*64..+64.
// MODE 0: tok||eff (N=1024/net, 8 n-tiles/net, P=1).   grid(chunk/64, 16)
// MODE 1: sup||dep (N=2048/net, 16 n-tiles/net, P=4/8). grid(chunk/64, 32)
// LDS swizzle: chunk c of row r at LDS chunk c ^ ((r>>1)&3); gload source
// pre-swizzled per-lane kc = (l&3) ^ ((l>>3)&3) (valid for 16-aligned bases).
// ---------------------------------------------------------------------------
template<int MODE>
__global__ __launch_bounds__(256, 4) void mfma2(
        const unsigned short* __restrict__ Xh, const unsigned short* __restrict__ Xl,
        const unsigned short* __restrict__ WhA, const unsigned short* __restrict__ WlA,
        const unsigned short* __restrict__ WhB, const unsigned short* __restrict__ WlB,
        const float* __restrict__ fixA, const float* __restrict__ fixB,
        const float* __restrict__ b1A, const float* __restrict__ b1B,
        const float* __restrict__ W2A, const float* __restrict__ W2B,
        const float* __restrict__ tokc, const float* __restrict__ ccp,
        const float* __restrict__ tkp,
        float* __restrict__ outA, float* __restrict__ outB, int m_base) {
    __shared__ unsigned short Ah[64 * 32], Al[64 * 32];    // 4 KiB each
    __shared__ unsigned short Bh[128 * 32], Bl[128 * 32];  // 8 KiB each

    constexpr int NBLK = (MODE == 0) ? 8 : 16;
    const int t = threadIdx.x;
    const int lane = t & 63;
    const int w = t >> 6;
    const int wave_m = (w & 1) * 32;
    const int wave_n = (w >> 1) * 64;
    const int m0l = blockIdx.x * 64;         // chunk-local row base (x = fastest)
    const int m0g = m_base + m0l;            // global row base (outputs)
    const int nb = (int)blockIdx.y;
    const int net = nb >= NBLK;
    const int n0 = (nb - (net ? NBLK : 0)) * 128;

    const unsigned short* Wth = net ? WhB : WhA;
    const unsigned short* Wtl = net ? WlB : WlA;

    // staging: wave w fills A rows [w*16, w*16+16) and B rows [w*32, w*32+32)
    const int sr = lane >> 2;                         // row within 16-row group
    const int kc = (lane & 3) ^ ((lane >> 3) & 3);    // pre-swizzled k-chunk
    size_t oA  = (size_t)(m0l + w * 16 + sr) * K_DIM + kc * 8;
    size_t oB0 = (size_t)(n0 + w * 32 + sr) * K_DIM + kc * 8;
    size_t oB1 = oB0 + (size_t)16 * K_DIM;
    const unsigned short* gAh  = Xh + oA;
    const unsigned short* gAl  = Xl + oA;
    const unsigned short* gBh0 = Wth + oB0; const unsigned short* gBh1 = Wth + oB1;
    const unsigned short* gBl0 = Wtl + oB0; const unsigned short* gBl1 = Wtl + oB1;
    const int ldA  = (w * 16) * 32;          // wave-uniform LDS elem offsets
    const int ldB0 = (w * 32) * 32;
    const int ldB1 = (w * 32 + 16) * 32;

    const int lr = lane & 15;
    const int kq = lane >> 4;
    const int coff = ((kq ^ ((lr >> 1) & 3)) * 8);

    f32x4 acc[2][4];
    #pragma unroll
    for (int i = 0; i < 2; i++)
        #pragma unroll
        for (int j = 0; j < 4; j++) acc[i][j] = (f32x4){0.f, 0.f, 0.f, 0.f};

    for (int k0 = 0; k0 < K_DIM; k0 += 32) {
        __syncthreads();                 // all waves done reading previous tile
        async16(&Ah[ldA], gAh + k0);
        async16(&Al[ldA], gAl + k0);
        async16(&Bh[ldB0], gBh0 + k0);  async16(&Bh[ldB1], gBh1 + k0);
        async16(&Bl[ldB0], gBl0 + k0);  async16(&Bl[ldB1], gBl1 + k0);
        __syncthreads();                 // vmcnt(0) drain -> tile visible

        bf16x8s ahf[2], alf[2];
        #pragma unroll
        for (int mt = 0; mt < 2; mt++) {
            int r = (wave_m + mt * 16 + lr) * 32 + coff;
            ahf[mt] = *(const bf16x8s*)&Ah[r];
            alf[mt] = *(const bf16x8s*)&Al[r];
        }
        #pragma unroll
        for (int nt = 0; nt < 4; nt++) {
            int rb = (wave_n + nt * 16 + lr) * 32 + coff;
            bf16x8s bh = *(const bf16x8s*)&Bh[rb];
            bf16x8s bl = *(const bf16x8s*)&Bl[rb];
            #pragma unroll
            for (int mt = 0; mt < 2; mt++) {
                acc[mt][nt] = __builtin_amdgcn_mfma_f32_16x16x32_bf16(ahf[mt], bh, acc[mt][nt], 0, 0, 0);
                acc[mt][nt] = __builtin_amdgcn_mfma_f32_16x16x32_bf16(ahf[mt], bl, acc[mt][nt], 0, 0, 0);
                acc[mt][nt] = __builtin_amdgcn_mfma_f32_16x16x32_bf16(alf[mt], bh, acc[mt][nt], 0, 0, 0);
            }
        }
    }

    // ---- bias / fixup / GELU
    const float* b1 = net ? b1B : b1A;
    float ccv = 0.f, tkv = 0.f;
    const float* fx = nullptr;
    if constexpr (MODE == 1) {
        int batch = m0g >> 12;               // 4096 rows per batch
        ccv = ccp[batch];
        tkv = tkp[batch];
        fx = net ? fixB : fixA;
    }
    #pragma unroll
    for (int mt = 0; mt < 2; mt++) {
        int mbase = m0g + wave_m + mt * 16 + kq * 4;
        f32x4 tc4 = (f32x4){0.f, 0.f, 0.f, 0.f};
        if constexpr (MODE == 1) tc4 = *(const f32x4*)&tokc[mbase];
        #pragma unroll
        for (int nt = 0; nt < 4; nt++) {
            int n = n0 + wave_n + nt * 16 + lr;
            float bias = b1[n];
            float f1 = 0.f, f2 = 0.f, f3 = 0.f;
            if constexpr (MODE == 1) {
                f1 = fx[(size_t)2048 * 2048 + n];
                f2 = fx[(size_t)2049 * 2048 + n];
                f3 = fx[(size_t)2050 * 2048 + n];
            }
            #pragma unroll
            for (int j = 0; j < 4; j++) {
                float h = acc[mt][nt][j] + bias;
                if constexpr (MODE == 1) h += tc4[j] * f1 + ccv * f2 + tkv * f3;
                acc[mt][nt][j] = gelu_f(h);
            }
        }
    }

    // ---- second layer + atomic accumulate
    if constexpr (MODE == 0) {
        epi<1>(acc, net ? W2B : W2A, net ? outB : outA, n0, wave_n, wave_m, m0g, lr, kq);
    } else {
        if (net == 0) epi<4>(acc, W2A, outA, n0, wave_n, wave_m, m0g, lr, kq);
        else          epi<8>(acc, W2B, outB, n0, wave_n, wave_m, m0g, lr, kq);
    }
}

// ---------------------------------------------------------------------------
// sigmoid of tok/eff logits for rows [row_base, row_base + grid*256)
__global__ __launch_bounds__(256) void finalize1(const float* __restrict__ ws,
                                                 float* __restrict__ dout,
                                                 int row_base) {
    int r = row_base + blockIdx.x * 256 + threadIdx.x;
    dout[OUT_TOKC + r] = sigmoid_f(ws[WS_TOKL + r]);
    dout[OUT_EFF + r]  = sigmoid_f(ws[WS_EFFL + r]);
}

// softmax + mask; flags rows whose sup_w is borderline-near 0.2 for fp32 repair
__global__ __launch_bounds__(256) void finalize2(float* __restrict__ ws,
                                                 float* __restrict__ dout) {
    int r = blockIdx.x * 256 + threadIdx.x;
    const float* sl = ws + WS_SUPL + (size_t)r * 4;
    float l[4];
    #pragma unroll
    for (int i = 0; i < 4; i++) l[i] = sl[i];
    float mx = fmaxf(fmaxf(l[0], l[1]), fmaxf(l[2], l[3]));
    float e[4], sum = 0.f;
    #pragma unroll
    for (int i = 0; i < 4; i++) { e[i] = expf(l[i] - mx); sum += e[i]; }
    float inv = 1.0f / sum;
    float eff = dout[OUT_EFF + r];
    bool flag = false;
    #pragma unroll
    for (int i = 0; i < 4; i++) {
        float wv = e[i] * inv;
        dout[OUT_SUPW + (size_t)r * 4 + i] = wv;
        dout[OUT_MASK + (size_t)r * 4 + i] = (wv > 0.2f) ? eff : 0.f;
        flag = flag || (fabsf(wv - 0.2f) < BAND);
    }
    if (flag) {
        int* cnt = (int*)(ws + WS_FLAGCNT);
        int* idx = (int*)(ws + WS_FLAGIDX);
        int slot = atomicAdd(cnt, 1);
        if (slot < NF_MAX) idx[slot] = r;
    }
    const float* dl = ws + WS_DEPL + (size_t)r * 8;
    float d[8];
    #pragma unroll
    for (int i = 0; i < 8; i++) d[i] = dl[i];
    float mx2 = d[0];
    #pragma unroll
    for (int i = 1; i < 8; i++) mx2 = fmaxf(mx2, d[i]);
    float sum2 = 0.f;
    #pragma unroll
    for (int i = 0; i < 8; i++) { d[i] = expf(d[i] - mx2); sum2 += d[i]; }
    float inv2 = 1.0f / sum2;
    #pragma unroll
    for (int i = 0; i < 8; i++)
        dout[OUT_DEPTH + (size_t)r * 8 + i] = d[i] * inv2;
}

// ---------------------------------------------------------------------------
// fp32 repair of sup logits for flagged rows.
// ---------------------------------------------------------------------------
__global__ __launch_bounds__(256) void repair_h(const float* __restrict__ X,
        const float* __restrict__ W1, const float* __restrict__ b1,
        const float* __restrict__ W2, const float* __restrict__ dout,
        const int* __restrict__ cntp, const int* __restrict__ idxp,
        float* __restrict__ rlog) {
    int cnt = *cntp; if (cnt > NF_MAX) cnt = NF_MAX;
    int rbase = blockIdx.y * 8;
    if (rbase >= cnt) return;
    int nr = cnt - rbase; if (nr > 8) nr = 8;

    __shared__ float Xs[8][2048];   // 64 KB
    __shared__ float HS[8][128];    // upper-k partial h

    const int t = threadIdx.x;
    const int w = t >> 6;
    const int lane = t & 63;
    const int joff = (w & 1) * 64 + lane;      // 0..127
    const int kh = w >> 1;                     // 0 or 1
    const int j = blockIdx.x * 128 + joff;

    int rows[8];
    #pragma unroll
    for (int rr = 0; rr < 8; rr++)
        rows[rr] = idxp[rbase + (rr < nr ? rr : 0)];

    for (int rr = 0; rr < nr; rr++) {
        const float4* src = (const float4*)(X + (size_t)rows[rr] * 2048);
        for (int c = t; c < 512; c += 256) ((float4*)Xs[rr])[c] = src[c];
    }
    for (int rr = nr; rr < 8; rr++)
        for (int c = t; c < 2048; c += 256) Xs[rr][c] = 0.f;
    __syncthreads();

    float h[8] = {0.f, 0.f, 0.f, 0.f, 0.f, 0.f, 0.f, 0.f};
    const float* Wcol = W1 + j;
    for (int k = kh * 1024; k < kh * 1024 + 1024; k += 4) {
        float w0 = Wcol[(size_t)(k + 0) * 2048];
        float w1 = Wcol[(size_t)(k + 1) * 2048];
        float w2 = Wcol[(size_t)(k + 2) * 2048];
        float w3 = Wcol[(size_t)(k + 3) * 2048];
        #pragma unroll
        for (int rr = 0; rr < 8; rr++) {
            float4 xv = *(const float4*)&Xs[rr][k];
            h[rr] = fmaf(xv.x, w0, h[rr]);
            h[rr] = fmaf(xv.y, w1, h[rr]);
            h[rr] = fmaf(xv.z, w2, h[rr]);
            h[rr] = fmaf(xv.w, w3, h[rr]);
        }
    }
    if (kh == 1) {
        #pragma unroll
        for (int rr = 0; rr < 8; rr++) HS[rr][joff] = h[rr];
    }
    __syncthreads();
    if (kh == 0) {
        float f1 = W1[(size_t)2048 * 2048 + j];
        float f2 = W1[(size_t)2049 * 2048 + j];
        float f3 = W1[(size_t)2050 * 2048 + j];
        float bj = b1[j];
        float4 w2v = *(const float4*)&W2[(size_t)j * 4];
        for (int rr = 0; rr < nr; rr++) {
            int r = rows[rr];
            float tc = dout[OUT_TOKC + r];
            float cc = dout[OUT_CTXC + (r >> 12)];
            float tk = dout[OUT_TASKC + (r >> 12)];
            float ht = h[rr] + HS[rr][joff] + tc * f1 + cc * f2 + tk * f3 + bj;
            float g = gelu_f(ht);
            float s0 = g * w2v.x, s1 = g * w2v.y, s2 = g * w2v.z, s3 = g * w2v.w;
            #pragma unroll
            for (int off = 1; off < 64; off <<= 1) {
                s0 += __shfl_xor(s0, off, 64);
                s1 += __shfl_xor(s1, off, 64);
                s2 += __shfl_xor(s2, off, 64);
                s3 += __shfl_xor(s3, off, 64);
            }
            if (lane == 0) {
                float* rl = rlog + (size_t)(rbase + rr) * 4;
                atomicAdd(&rl[0], s0);
                atomicAdd(&rl[1], s1);
                atomicAdd(&rl[2], s2);
                atomicAdd(&rl[3], s3);
            }
        }
    }
}

// overwrite supw + mask rows for flagged tokens from fp32 logits
__global__ __launch_bounds__(256) void repair_fin(const int* __restrict__ cntp,
        const int* __restrict__ idxp, const float* __restrict__ rlog,
        float* __restrict__ dout) {
    int cnt = *cntp; if (cnt > NF_MAX) cnt = NF_MAX;
    int slot = blockIdx.x * 256 + threadIdx.x;
    if (slot >= cnt) return;
    int r = idxp[slot];
    float l[4];
    #pragma unroll
    for (int i = 0; i < 4; i++) l[i] = rlog[(size_t)slot * 4 + i];
    float mx = fmaxf(fmaxf(l[0], l[1]), fmaxf(l[2], l[3]));
    float e[4], sum = 0.f;
    #pragma unroll
    for (int i = 0; i < 4; i++) { e[i] = expf(l[i] - mx); sum += e[i]; }
    float inv = 1.0f / sum;
    float eff = dout[OUT_EFF + r];
    #pragma unroll
    for (int i = 0; i < 4; i++) {
        float wv = e[i] * inv;
        dout[OUT_SUPW + (size_t)r * 4 + i] = wv;
        dout[OUT_MASK + (size_t)r * 4 + i] = (wv > 0.2f) ? eff : 0.f;
    }
}

// ---------------------------------------------------------------------------
extern "C" void kernel_launch(void* const* d_in, const int* in_sizes, int n_in,
                              void* d_out, int out_size, void* d_ws, size_t ws_size,
                              hipStream_t stream) {
    const float* X      = (const float*)d_in[0];
    const float* tokW1  = (const float*)d_in[1];
    const float* tokb1  = (const float*)d_in[2];
    const float* tokW2  = (const float*)d_in[3];
    const float* tokb2  = (const float*)d_in[4];
    const float* ctxW1  = (const float*)d_in[5];
    const float* ctxb1  = (const float*)d_in[6];
    const float* ctxW2  = (const float*)d_in[7];
    const float* ctxb2  = (const float*)d_in[8];
    const float* taskW1 = (const float*)d_in[9];
    const float* taskb1 = (const float*)d_in[10];
    const float* taskW2 = (const float*)d_in[11];
    const float* taskb2 = (const float*)d_in[12];
    const float* effW1  = (const float*)d_in[13];
    const float* effb1  = (const float*)d_in[14];
    const float* effW2  = (const float*)d_in[15];
    const float* effb2  = (const float*)d_in[16];
    const float* supW1  = (const float*)d_in[17];
    const float* supb1  = (const float*)d_in[18];
    const float* supW2  = (const float*)d_in[19];
    const float* supb2  = (const float*)d_in[20];
    const float* depW1  = (const float*)d_in[21];
    const float* depb1  = (const float*)d_in[22];
    const float* depW2  = (const float*)d_in[23];
    const float* depb2  = (const float*)d_in[24];
    float* out = (float*)d_out;
    float* ws  = (float*)d_ws;
    char*  wsb = (char*)d_ws;

    // Phase A pointers
    unsigned short* tokh = (unsigned short*)(wsb + PA_TOKH);
    unsigned short* tokl = (unsigned short*)(wsb + PA_TOKL);
    unsigned short* effh = (unsigned short*)(wsb + PA_EFFH);
    unsigned short* effl = (unsigned short*)(wsb + PA_EFFL);
    unsigned short* xa   = (unsigned short*)(wsb + PA_X);
    unsigned short* xal  = xa + (size_t)CHUNK_A * H_DIM;
    // Phase B pointers (overlap phase A region; stream-ordered)
    unsigned short* suph = (unsigned short*)(wsb + PB_SUPH);
    unsigned short* supl = (unsigned short*)(wsb + PB_SUPL);
    unsigned short* deph = (unsigned short*)(wsb + PB_DEPH);
    unsigned short* depl = (unsigned short*)(wsb + PB_DEPL);
    unsigned short* xb   = (unsigned short*)(wsb + PB_X);
    unsigned short* xbl  = xb + (size_t)CHUNK_B * H_DIM;

    const int* cntp = (const int*)(ws + WS_FLAGCNT);
    const int* idxp = (const int*)(ws + WS_FLAGIDX);
    float* rlog = ws + WS_RLOG;

    init_ws<<<(WS_TOTAL + 255) / 256, 256, 0, stream>>>(ws, tokb2, effb2, supb2, depb2);
    mean_kernel<<<dim3(8, 32, 4), 256, 0, stream>>>(X, ws + WS_CTXSUM);
    ctx_task_h<<<dim3(4, 4, 2), 256, 0, stream>>>(ws + WS_CTXSUM, ctxW1, ctxb1,
                                                  taskW1, taskb1, ws + WS_HBUF);
    ctx_task_out<<<dim3(4, 2), 256, 0, stream>>>(ws + WS_HBUF, ctxW2, ctxb2,
                                                 taskW2, taskb2, out);

    // ---- Phase A: tok + eff ----
    transpose_split<<<dim3(32, 16), 256, 0, stream>>>(tokW1, tokh, tokl, 1024);
    transpose_split<<<dim3(32, 16), 256, 0, stream>>>(effW1, effh, effl, 1024);
    for (int c0 = 0; c0 < M_TOT; c0 += CHUNK_A) {
        split_x<<<CHUNK_A, 256, 0, stream>>>(X, xa, xal, c0);
        mfma2<0><<<dim3(CHUNK_A / 64, 16), 256, 0, stream>>>(
            xa, xal, tokh, tokl, effh, effl,
            nullptr, nullptr, tokb1, effb1, tokW2, effW2,
            nullptr, nullptr, nullptr,
            ws + WS_TOKL, ws + WS_EFFL, c0);
        finalize1<<<CHUNK_A / 256, 256, 0, stream>>>(ws, out, c0);
    }

    // ---- Phase B: sup + dep (weights overwrite phase A area) ----
    transpose_split<<<dim3(32, 32), 256, 0, stream>>>(supW1, suph, supl, 2048);
    transpose_split<<<dim3(32, 32), 256, 0, stream>>>(depW1, deph, depl, 2048);
    for (int c0 = 0; c0 < M_TOT; c0 += CHUNK_B) {
        split_x<<<CHUNK_B, 256, 0, stream>>>(X, xb, xbl, c0);
        mfma2<1><<<dim3(CHUNK_B / 64, 32), 256, 0, stream>>>(
            xb, xbl, suph, supl, deph, depl,
            supW1, depW1, supb1, depb1, supW2, depW2,
            out + OUT_TOKC, out + OUT_CTXC, out + OUT_TASKC,
            ws + WS_SUPL, ws + WS_DEPL, c0);
    }

    finalize2<<<64, 256, 0, stream>>>(ws, out);
    repair_h<<<dim3(16, NF_MAX / 8), 256, 0, stream>>>(
        X, supW1, supb1, supW2, out, cntp, idxp, rlog);
    repair_fin<<<NF_MAX / 256, 256, 0, stream>>>(cntp, idxp, rlog, out);
}